// Round 17
// baseline (108.038 us; speedup 1.0000x reference)
//
#include <hip/hip_runtime.h>

typedef short  short8  __attribute__((ext_vector_type(8)));
typedef short  short4v __attribute__((ext_vector_type(4)));
typedef float  float4v __attribute__((ext_vector_type(4)));
typedef int    int4v   __attribute__((ext_vector_type(4)));
typedef int    int2v   __attribute__((ext_vector_type(2)));

#define LOG2E 1.4426950408889634f

static __device__ __forceinline__ short f2bf(float f) {
  unsigned u = __builtin_bit_cast(unsigned, f);
  u = (u + 0x7fffu + ((u >> 16) & 1u)) >> 16;   // RNE
  return (short)u;
}
static __device__ __forceinline__ float bf2f(short s) {
  return __builtin_bit_cast(float, ((unsigned)(unsigned short)s) << 16);
}

typedef __attribute__((address_space(3))) char  as3c;
typedef __attribute__((address_space(1))) char  as1c;
static __device__ __forceinline__ void dma16(const void* g, void* l) {
  __builtin_amdgcn_global_load_lds((const as1c*)g, (as3c*)l, 16, 0, 0);
}

// ---------------------------------------------------------------------------
// Kernel 1: h = x @ w.T  (8192x256, K=256), hi/lo bf16-split MFMA for ~f32
// accuracy. BM=32 -> 256 blocks (full chip). Writes hT bf16 [256][8192] and
// — fused — the score vectors s1 = h@a1, s2 = h@a2 (block owns full rows,
// so the reduction closes in-block via LDS).
// ---------------------------------------------------------------------------
__global__ __launch_bounds__(256) void k_hgemm(
    const float* __restrict__ x, const float* __restrict__ w,
    const float* __restrict__ a, short* __restrict__ hT,
    float* __restrict__ s1, float* __restrict__ s2) {
  __shared__ float zl1[2048], zl2[2048];      // 32 rows x 64 partials
  const int I0   = blockIdx.x * 32;
  const int tid  = threadIdx.x;
  const int lane = tid & 63;
  const int wn   = tid >> 6;               // 4 waves split N (cols)
  const int lrow = lane & 15;
  const int lk8  = (lane >> 4) << 3;

  float a1c[4], a2c[4];
  #pragma unroll
  for (int ni = 0; ni < 4; ++ni) {
    const int col = wn * 64 + ni * 16 + lrow;
    a1c[ni] = a[col];
    a2c[ni] = a[256 + col];
  }

  float4v zero4 = {0.f, 0.f, 0.f, 0.f};
  float4v acc[2][4];
  #pragma unroll
  for (int mi = 0; mi < 2; ++mi)
    #pragma unroll
    for (int ni = 0; ni < 4; ++ni) acc[mi][ni] = zero4;

  for (int k0 = 0; k0 < 256; k0 += 32) {
    short8 ah[2], al[2], bh[4], bl[4];
    #pragma unroll
    for (int mi = 0; mi < 2; ++mi) {
      const float* xp = x + (size_t)(I0 + mi * 16 + lrow) * 256 + k0 + lk8;
      float4v va = *(const float4v*)xp;
      float4v vb = *(const float4v*)(xp + 4);
      #pragma unroll
      for (int e = 0; e < 4; ++e) {
        short h = f2bf(va[e]); ah[mi][e] = h;     al[mi][e]     = f2bf(va[e] - bf2f(h));
        h = f2bf(vb[e]);       ah[mi][4 + e] = h; al[mi][4 + e] = f2bf(vb[e] - bf2f(h));
      }
    }
    #pragma unroll
    for (int ni = 0; ni < 4; ++ni) {
      const float* wp = w + (size_t)(wn * 64 + ni * 16 + lrow) * 256 + k0 + lk8;
      float4v va = *(const float4v*)wp;
      float4v vb = *(const float4v*)(wp + 4);
      #pragma unroll
      for (int e = 0; e < 4; ++e) {
        short h = f2bf(va[e]); bh[ni][e] = h;     bl[ni][e]     = f2bf(va[e] - bf2f(h));
        h = f2bf(vb[e]);       bh[ni][4 + e] = h; bl[ni][4 + e] = f2bf(vb[e] - bf2f(h));
      }
    }
    #pragma unroll
    for (int mi = 0; mi < 2; ++mi)
      #pragma unroll
      for (int ni = 0; ni < 4; ++ni) {
        acc[mi][ni] = __builtin_amdgcn_mfma_f32_16x16x32_bf16(al[mi], bh[ni], acc[mi][ni], 0, 0, 0);
        acc[mi][ni] = __builtin_amdgcn_mfma_f32_16x16x32_bf16(ah[mi], bl[ni], acc[mi][ni], 0, 0, 0);
        acc[mi][ni] = __builtin_amdgcn_mfma_f32_16x16x32_bf16(ah[mi], bh[ni], acc[mi][ni], 0, 0, 0);
      }
  }

  const int r0 = (lane >> 4) << 2;   // C/D: col=lane&15, row=(lane>>4)*4+reg
  #pragma unroll
  for (int mi = 0; mi < 2; ++mi) {
    #pragma unroll
    for (int ni = 0; ni < 4; ++ni) {
      const int c   = wn * 64 + ni * 16 + lrow;
      const int row = I0 + mi * 16 + r0;
      float4v v = acc[mi][ni];
      short4v sv;
      #pragma unroll
      for (int r = 0; r < 4; ++r) sv[r] = f2bf(v[r]);
      *(short4v*)(hT + (size_t)c * 8192 + row) = sv;
    }
    #pragma unroll
    for (int r = 0; r < 4; ++r) {
      const int srow = mi * 16 + r0 + r;
      float p1 = 0.f, p2 = 0.f;
      #pragma unroll
      for (int ni = 0; ni < 4; ++ni) {
        p1 = fmaf(acc[mi][ni][r], a1c[ni], p1);
        p2 = fmaf(acc[mi][ni][r], a2c[ni], p2);
      }
      const int gcol = wn * 16 + lrow;
      zl1[srow * 64 + gcol] = p1;
      zl2[srow * 64 + gcol] = p2;
    }
  }
  __syncthreads();
  if (tid < 32) {
    float v1 = 0.f, v2 = 0.f;
    #pragma unroll
    for (int g = 0; g < 64; ++g) {
      const int gg = (g + tid) & 63;       // rotate to avoid bank conflicts
      v1 += zl1[tid * 64 + gg];
      v2 += zl2[tid * 64 + gg];
    }
    s1[I0 + tid] = v1;
    s2[I0 + tid] = v2;
  }
}

// ---------------------------------------------------------------------------
// Kernel 2: emit exp2 tables from s1,s2:
//   e1f1[i] = {exp2(t1), exp2(0.2 t1)},  ef2[j] = {exp2(t2), exp2(0.2 t2)}
// so W = adj ? max(e1*e2, f1*f2) : 1  (exp2 of leaky-relu separable via
// monotonicity — no per-element transcendental in k_gat).
// ---------------------------------------------------------------------------
__global__ __launch_bounds__(256) void k_scores2(
    const float* __restrict__ s1, const float* __restrict__ s2,
    float2* __restrict__ e1f1, float2* __restrict__ ef2) {
  const int i = blockIdx.x * 256 + threadIdx.x;
  const float t1 = LOG2E * s1[i];
  const float t2 = LOG2E * s2[i];
  e1f1[i] = make_float2(exp2f(t1), exp2f(0.2f * t1));
  ef2[i]  = make_float2(exp2f(t2), exp2f(0.2f * t2));
}

// ---------------------------------------------------------------------------
// Kernel 4: fused GAT GEMM — r14/r16 counted-vmcnt pipeline (103.7 µs total
// reproduced), single change: adj loads are PLAIN (nt removed). Probe: nt
// marks the stream non-temporal in cache; adj (268 MB) nearly fits the
// 256 MB L3 across graph replays, and FETCH 150 MB < 268 MB shows L3
// already serves ~45%. Plain loads may raise L3/L2 residency -> faster adj
// delivery (the modeled k_gat bound). vmcnt protocol counts loads, not
// cache policy — schedule unchanged. Decision rule: total >= 103 µs next
// round reverts + declares roofline.
// ---------------------------------------------------------------------------
__global__ __launch_bounds__(512) void k_gat(
    const int* __restrict__ adj, const short* __restrict__ hT,
    const float2* __restrict__ e1f1, const float2* __restrict__ ef2,
    float* __restrict__ Np, float* __restrict__ Zp) {
  __shared__ __align__(16) char Wt[2][17408];   // 128 rows x 136B (64j bf16 + 8B pad)
  __shared__ __align__(16) char Hb[2][32768];   // 256 rows x 128B, linear, src-swz
  __shared__ __align__(16) char Elds[16384];    // ef2 slab: 2048 x {e,f} f32

  const int tid = threadIdx.x, lane = tid & 63, wave = tid >> 6;
  const int wm = wave >> 2, wn = wave & 3;
  const int lrow = lane & 15, lk16 = (lane >> 4) << 4;
  // XCD remap: same-XCD blocks (bid mod 8) share by -> shared j-window in L2
  const int bid = blockIdx.y * 64 + blockIdx.x;
  const int bx = bid >> 2, by = bid & 3;
  const int I0 = bx * 128;
  const int j0 = by * 2048;

  // --- W staging map: thread -> rows ar+32p (p=0..3), 4-j chunk aj
  const int ar = tid >> 4, aj = tid & 15;
  const int* agp = adj + (size_t)(I0 + ar) * 8192 + j0 + aj * 4;
  float e1p[4], f1p[4];
  #pragma unroll
  for (int p = 0; p < 4; ++p) {
    float2 v = e1f1[I0 + p * 32 + ar];
    e1p[p] = v.x; f1p[p] = v.y;
  }
  const int wwo = ar * 136 + aj * 8;            // + p*4352, + buf

  // --- H DMA: wave -> rows wave*32..+31; lane l -> row +(l>>3),
  //     global chunk (l&7)^(l>>3) (pre-swizzle; LDS stays linear)
  const int l8 = lane >> 3, l7 = lane & 7;
  const short* hdma = hT + (size_t)(wave * 32 + l8) * 8192 + j0 + (l7 ^ l8) * 8;
  const int hlo = wave * 4096;                  // + q*1024, + buf

  // --- frag-read bases
  const int ardo = (wm * 64 + lrow) * 136 + lk16;      // + mi*2176 + kk*64
  const int brdo = (wn * 64 + lrow) * 128;             // + ni*2048 + (c0 ^ kk<<6)
  const int c0   = ((lane >> 4) ^ (lrow & 7)) << 4;

  float4v zero4 = {0.f, 0.f, 0.f, 0.f};
  float4v acc[4][4];
  #pragma unroll
  for (int mi = 0; mi < 4; ++mi)
    #pragma unroll
    for (int ni = 0; ni < 4; ++ni) acc[mi][ni] = zero4;
  float zacc[4] = {0.f, 0.f, 0.f, 0.f};
  int4v ga[4];

  // W-compute for tile T from ga + Elds, writes to DST (Wt buffer base)
#define WCOMP(T, DST)                                                         \
  { const float4v ge0 = *(const float4v*)(Elds + (T) * 512 + aj * 32);        \
    const float4v ge1 = *(const float4v*)(Elds + (T) * 512 + aj * 32 + 16);   \
    _Pragma("unroll")                                                         \
    for (int p = 0; p < 4; ++p) {                                             \
      float w0 = ga[p][0] ? fmaxf(e1p[p] * ge0[0], f1p[p] * ge0[1]) : 1.0f;   \
      float w1 = ga[p][1] ? fmaxf(e1p[p] * ge0[2], f1p[p] * ge0[3]) : 1.0f;   \
      float w2 = ga[p][2] ? fmaxf(e1p[p] * ge1[0], f1p[p] * ge1[1]) : 1.0f;   \
      float w3 = ga[p][3] ? fmaxf(e1p[p] * ge1[2], f1p[p] * ge1[3]) : 1.0f;   \
      zacc[p] += (w0 + w1) + (w2 + w3);                                       \
      int2v pw;                                                               \
      asm("v_cvt_pk_bf16_f32 %0, %1, %2" : "=v"(pw[0]) : "v"(w0), "v"(w1));   \
      asm("v_cvt_pk_bf16_f32 %0, %1, %2" : "=v"(pw[1]) : "v"(w2), "v"(w3));   \
      *(int2v*)((DST) + wwo + p * 4352) = pw;                                 \
    } }

  // --- prologue: ef table -> LDS; tile-0 staging; counted-wait barrier
  {
    const char* esrc = (const char*)(ef2 + j0);
    *(float4v*)(Elds + tid * 32)      = *(const float4v*)(esrc + tid * 32);
    *(float4v*)(Elds + tid * 32 + 16) = *(const float4v*)(esrc + tid * 32 + 16);
  }
  __syncthreads();                              // Elds visible
  #pragma unroll
  for (int p = 0; p < 4; ++p)
    ga[p] = *(const int4v*)(agp + (size_t)p * 262144);
  __builtin_amdgcn_sched_barrier(0);            // pin: adj0 issued first
  #pragma unroll
  for (int q = 0; q < 4; ++q)
    dma16(hdma + q * 65536, Hb[0] + hlo + q * 1024);
  __builtin_amdgcn_sched_barrier(0);            // pin: DMAs before adj1
  WCOMP(0, Wt[0]);
  #pragma unroll
  for (int p = 0; p < 4; ++p)
    ga[p] = *(const int4v*)(agp + (size_t)p * 262144 + 64);
  __builtin_amdgcn_sched_barrier(0);            // pin: adj1 after DMAs
  asm volatile("s_waitcnt vmcnt(4) lgkmcnt(0)" ::: "memory");
  __builtin_amdgcn_s_barrier();
  __builtin_amdgcn_sched_barrier(0);

  #pragma unroll 2
  for (int s = 0; s < 32; ++s) {
    const int cur = s & 1, nx = cur ^ 1;
    // P1: DMA H(s+1) into Hb[nx]
    if (s < 31) {
      const int so = (s + 1) * 64;              // shorts
      #pragma unroll
      for (int q = 0; q < 4; ++q)
        dma16(hdma + so + q * 65536, Hb[nx] + hlo + q * 1024);
    }
    __builtin_amdgcn_sched_barrier(0);          // pin: DMA group issued here
    // P2: kk=0 frags + 16 MFMA
    short8 af[4], bf[4];
    #pragma unroll
    for (int mi = 0; mi < 4; ++mi) af[mi] = *(const short8*)(Wt[cur] + ardo + mi * 2176);
    #pragma unroll
    for (int ni = 0; ni < 4; ++ni) bf[ni] = *(const short8*)(Hb[cur] + brdo + ni * 2048 + c0);
    #pragma unroll
    for (int mi = 0; mi < 4; ++mi)
      #pragma unroll
      for (int ni = 0; ni < 4; ++ni)
        acc[mi][ni] = __builtin_amdgcn_mfma_f32_16x16x32_bf16(af[mi], bf[ni], acc[mi][ni], 0, 0, 0);
    // P3: W-compute(s+1) -> Wt[nx] (VALU covers the DMA in flight)
    if (s < 31) WCOMP(s + 1, Wt[nx]);
    // P4: issue adj — EVERY s<31 (clamped) so each barrier has exactly 4
    //     adj ops in flight behind the 4 DMAs (vmcnt(4) drains DMAs only)
    if (s < 31) {
      const int sp = (s + 2 < 32) ? s + 2 : 31;
      const int so = sp * 64;                   // ints
      #pragma unroll
      for (int p = 0; p < 4; ++p)
        ga[p] = *(const int4v*)(agp + (size_t)p * 262144 + so);
    }
    __builtin_amdgcn_sched_barrier(0);          // pin: adj group after DMAs
    // P5: kk=1 frags + 16 MFMA
    #pragma unroll
    for (int mi = 0; mi < 4; ++mi) af[mi] = *(const short8*)(Wt[cur] + ardo + mi * 2176 + 64);
    #pragma unroll
    for (int ni = 0; ni < 4; ++ni) bf[ni] = *(const short8*)(Hb[cur] + brdo + ni * 2048 + (c0 ^ 64));
    #pragma unroll
    for (int mi = 0; mi < 4; ++mi)
      #pragma unroll
      for (int ni = 0; ni < 4; ++ni)
        acc[mi][ni] = __builtin_amdgcn_mfma_f32_16x16x32_bf16(af[mi], bf[ni], acc[mi][ni], 0, 0, 0);
    // P6: counted drain (DMAs only; adj loads stay in flight) + raw barrier
    if (s < 31) {
      asm volatile("s_waitcnt vmcnt(4) lgkmcnt(0)" ::: "memory");
      __builtin_amdgcn_s_barrier();
      __builtin_amdgcn_sched_barrier(0);
    }
  }
#undef WCOMP

  // Z reduce: per-thread partials -> LDS (alias over Elds) -> 1/row
  __syncthreads();
  float* zl = (float*)Elds;
  #pragma unroll
  for (int p = 0; p < 4; ++p) zl[(ar + p * 32) * 16 + aj] = zacc[p];
  __syncthreads();
  if (tid < 128) {
    float z = 0.f;
    #pragma unroll
    for (int g = 0; g < 16; ++g) z += zl[tid * 16 + g];
    Zp[(size_t)by * 8192 + I0 + tid] = z;
  }

  // N partial store (direct, no atomics)
  float* Npb = Np + (size_t)by * 2097152;
  const int r0 = (lane >> 4) << 2;
  #pragma unroll
  for (int mi = 0; mi < 4; ++mi) {
    const int rowb = I0 + wm * 64 + mi * 16 + r0;
    #pragma unroll
    for (int ni = 0; ni < 4; ++ni) {
      const int col = wn * 64 + ni * 16 + lrow;
      #pragma unroll
      for (int r = 0; r < 4; ++r)
        Npb[(size_t)(rowb + r) * 256 + col] = acc[mi][ni][r];
    }
  }
}

// ---------------------------------------------------------------------------
// Kernel 5: out = elu( (sum_y Np) / (sum_y Zp) )   (4 split-K slabs)
// ---------------------------------------------------------------------------
__global__ __launch_bounds__(256) void k_out(
    const float* __restrict__ Np, const float* __restrict__ Zp,
    float* __restrict__ out) {
  const int idx = blockIdx.x * 256 + threadIdx.x;   // float4 index
  const int i = idx >> 6;                           // row (256 feat = 64 f4)
  float z = 0.f;
  #pragma unroll
  for (int y = 0; y < 4; ++y) z += Zp[y * 8192 + i];
  float4v n = {0.f, 0.f, 0.f, 0.f};
  #pragma unroll
  for (int y = 0; y < 4; ++y) {
    float4v v = ((const float4v*)Np)[(size_t)y * 524288 + idx];
    #pragma unroll
    for (int e = 0; e < 4; ++e) n[e] += v[e];
  }
  const float rz = 1.0f / z;
  float4v o;
  #pragma unroll
  for (int e = 0; e < 4; ++e) {
    float v = n[e] * rz;
    o[e] = (v > 0.f) ? v : expm1f(v);
  }
  ((float4v*)out)[idx] = o;
}

// ---------------------------------------------------------------------------
extern "C" void kernel_launch(void* const* d_in, const int* in_sizes, int n_in,
                              void* d_out, int out_size, void* d_ws, size_t ws_size,
                              hipStream_t stream) {
  const int*   adj = (const int*)d_in[0];
  const float* x   = (const float*)d_in[1];
  const float* w   = (const float*)d_in[2];
  const float* a   = (const float*)d_in[3];
  float* out = (float*)d_out;

  // ws layout (~48 MiB of ~1 GiB). d_out is written only by k_out.
  char* ws = (char*)d_ws;
  short*  hT   = (short*)(ws + 0);          //  4 MiB bf16 h^T [256][8192]
  float*  s1   = (float*)(ws + 4194304);    // 32 KiB
  float*  s2   = (float*)(ws + 4259840);    // 32 KiB
  float2* e1f1 = (float2*)(ws + 4325376);   // 64 KiB
  float2* ef2  = (float2*)(ws + 4390912);   // 64 KiB
  float*  Zp   = (float*)(ws + 4456448);    // 128 KiB (4 x 8192)
  float*  Np   = (float*)(ws + 16777216);   // 32 MiB (4 x 8192 x 256)

  k_hgemm  <<<256, 256, 0, stream>>>(x, w, a, hT, s1, s2);
  k_scores2<<<32, 256, 0, stream>>>(s1, s2, e1f1, ef2);
  k_gat    <<<dim3(64, 4), 512, 0, stream>>>(adj, hT, e1f1, ef2, Np, Zp);
  k_out    <<<2048, 256, 0, stream>>>(Np, Zp, out);
}

// Round 18
// 102.108 us; speedup vs baseline: 1.0581x; 1.0581x over previous
//
#include <hip/hip_runtime.h>

typedef short  short8  __attribute__((ext_vector_type(8)));
typedef short  short4v __attribute__((ext_vector_type(4)));
typedef float  float4v __attribute__((ext_vector_type(4)));
typedef int    int4v   __attribute__((ext_vector_type(4)));
typedef int    int2v   __attribute__((ext_vector_type(2)));

#define LOG2E 1.4426950408889634f

static __device__ __forceinline__ short f2bf(float f) {
  unsigned u = __builtin_bit_cast(unsigned, f);
  u = (u + 0x7fffu + ((u >> 16) & 1u)) >> 16;   // RNE
  return (short)u;
}
static __device__ __forceinline__ float bf2f(short s) {
  return __builtin_bit_cast(float, ((unsigned)(unsigned short)s) << 16);
}

typedef __attribute__((address_space(3))) char  as3c;
typedef __attribute__((address_space(1))) char  as1c;
static __device__ __forceinline__ void dma16(const void* g, void* l) {
  __builtin_amdgcn_global_load_lds((const as1c*)g, (as3c*)l, 16, 0, 0);
}

// ---------------------------------------------------------------------------
// Kernel 1: h = x @ w.T  (8192x256, K=256), hi/lo bf16-split MFMA for ~f32
// accuracy. BM=32 -> 256 blocks (full chip). Writes hT bf16 [256][8192] and
// — fused — the score vectors s1 = h@a1, s2 = h@a2 (block owns full rows,
// so the reduction closes in-block via LDS).
// ---------------------------------------------------------------------------
__global__ __launch_bounds__(256) void k_hgemm(
    const float* __restrict__ x, const float* __restrict__ w,
    const float* __restrict__ a, short* __restrict__ hT,
    float* __restrict__ s1, float* __restrict__ s2) {
  __shared__ float zl1[2048], zl2[2048];      // 32 rows x 64 partials
  const int I0   = blockIdx.x * 32;
  const int tid  = threadIdx.x;
  const int lane = tid & 63;
  const int wn   = tid >> 6;               // 4 waves split N (cols)
  const int lrow = lane & 15;
  const int lk8  = (lane >> 4) << 3;

  float a1c[4], a2c[4];
  #pragma unroll
  for (int ni = 0; ni < 4; ++ni) {
    const int col = wn * 64 + ni * 16 + lrow;
    a1c[ni] = a[col];
    a2c[ni] = a[256 + col];
  }

  float4v zero4 = {0.f, 0.f, 0.f, 0.f};
  float4v acc[2][4];
  #pragma unroll
  for (int mi = 0; mi < 2; ++mi)
    #pragma unroll
    for (int ni = 0; ni < 4; ++ni) acc[mi][ni] = zero4;

  for (int k0 = 0; k0 < 256; k0 += 32) {
    short8 ah[2], al[2], bh[4], bl[4];
    #pragma unroll
    for (int mi = 0; mi < 2; ++mi) {
      const float* xp = x + (size_t)(I0 + mi * 16 + lrow) * 256 + k0 + lk8;
      float4v va = *(const float4v*)xp;
      float4v vb = *(const float4v*)(xp + 4);
      #pragma unroll
      for (int e = 0; e < 4; ++e) {
        short h = f2bf(va[e]); ah[mi][e] = h;     al[mi][e]     = f2bf(va[e] - bf2f(h));
        h = f2bf(vb[e]);       ah[mi][4 + e] = h; al[mi][4 + e] = f2bf(vb[e] - bf2f(h));
      }
    }
    #pragma unroll
    for (int ni = 0; ni < 4; ++ni) {
      const float* wp = w + (size_t)(wn * 64 + ni * 16 + lrow) * 256 + k0 + lk8;
      float4v va = *(const float4v*)wp;
      float4v vb = *(const float4v*)(wp + 4);
      #pragma unroll
      for (int e = 0; e < 4; ++e) {
        short h = f2bf(va[e]); bh[ni][e] = h;     bl[ni][e]     = f2bf(va[e] - bf2f(h));
        h = f2bf(vb[e]);       bh[ni][4 + e] = h; bl[ni][4 + e] = f2bf(vb[e] - bf2f(h));
      }
    }
    #pragma unroll
    for (int mi = 0; mi < 2; ++mi)
      #pragma unroll
      for (int ni = 0; ni < 4; ++ni) {
        acc[mi][ni] = __builtin_amdgcn_mfma_f32_16x16x32_bf16(al[mi], bh[ni], acc[mi][ni], 0, 0, 0);
        acc[mi][ni] = __builtin_amdgcn_mfma_f32_16x16x32_bf16(ah[mi], bl[ni], acc[mi][ni], 0, 0, 0);
        acc[mi][ni] = __builtin_amdgcn_mfma_f32_16x16x32_bf16(ah[mi], bh[ni], acc[mi][ni], 0, 0, 0);
      }
  }

  const int r0 = (lane >> 4) << 2;   // C/D: col=lane&15, row=(lane>>4)*4+reg
  #pragma unroll
  for (int mi = 0; mi < 2; ++mi) {
    #pragma unroll
    for (int ni = 0; ni < 4; ++ni) {
      const int c   = wn * 64 + ni * 16 + lrow;
      const int row = I0 + mi * 16 + r0;
      float4v v = acc[mi][ni];
      short4v sv;
      #pragma unroll
      for (int r = 0; r < 4; ++r) sv[r] = f2bf(v[r]);
      *(short4v*)(hT + (size_t)c * 8192 + row) = sv;
    }
    #pragma unroll
    for (int r = 0; r < 4; ++r) {
      const int srow = mi * 16 + r0 + r;
      float p1 = 0.f, p2 = 0.f;
      #pragma unroll
      for (int ni = 0; ni < 4; ++ni) {
        p1 = fmaf(acc[mi][ni][r], a1c[ni], p1);
        p2 = fmaf(acc[mi][ni][r], a2c[ni], p2);
      }
      const int gcol = wn * 16 + lrow;
      zl1[srow * 64 + gcol] = p1;
      zl2[srow * 64 + gcol] = p2;
    }
  }
  __syncthreads();
  if (tid < 32) {
    float v1 = 0.f, v2 = 0.f;
    #pragma unroll
    for (int g = 0; g < 64; ++g) {
      const int gg = (g + tid) & 63;       // rotate to avoid bank conflicts
      v1 += zl1[tid * 64 + gg];
      v2 += zl2[tid * 64 + gg];
    }
    s1[I0 + tid] = v1;
    s2[I0 + tid] = v2;
  }
}

// ---------------------------------------------------------------------------
// Kernel 2: emit exp2 tables from s1,s2:
//   e1f1[i] = {exp2(t1), exp2(0.2 t1)},  ef2[j] = {exp2(t2), exp2(0.2 t2)}
// so W = adj ? max(e1*e2, f1*f2) : 1  (exp2 of leaky-relu separable via
// monotonicity — no per-element transcendental in k_gat).
// ---------------------------------------------------------------------------
__global__ __launch_bounds__(256) void k_scores2(
    const float* __restrict__ s1, const float* __restrict__ s2,
    float2* __restrict__ e1f1, float2* __restrict__ ef2) {
  const int i = blockIdx.x * 256 + threadIdx.x;
  const float t1 = LOG2E * s1[i];
  const float t2 = LOG2E * s2[i];
  e1f1[i] = make_float2(exp2f(t1), exp2f(0.2f * t1));
  ef2[i]  = make_float2(exp2f(t2), exp2f(0.2f * t2));
}

// ---------------------------------------------------------------------------
// Kernel 4: fused GAT GEMM — the measured optimum (r14/r16, 103.7 µs total),
// restored after the r17 nt-probe regressed (+4.3 µs: nt protects hT's L2
// residency from the 268 MB adj stream). Counted-vmcnt pipeline (T3/T4):
// one raw s_barrier per tile with s_waitcnt vmcnt(4) — drains the 4 H-DMAs,
// keeps 4 adj NT loads in flight ACROSS the barrier. sched_barrier(0) pins
// issue groups (r11 race lesson). XCD remap: by = bid&3 gives each XCD one
// j-window -> 1 MB hT slice L2-resident. BM=128 BN=256 BK=64, split-K=4:
// grid (64,4)=256 blocks = 1/CU, 114KB LDS (Wt[2] 136B-pad rows + Hb[2]
// linear/DMA src-swizzled + ef table in LDS).
// Neighborhood measured: BK=32 +52µs, BM=256 +62µs, 2-blk/CU +52µs,
// no-nt +4µs, __syncthreads-variants +40µs — all regress.
// ---------------------------------------------------------------------------
__global__ __launch_bounds__(512) void k_gat(
    const int* __restrict__ adj, const short* __restrict__ hT,
    const float2* __restrict__ e1f1, const float2* __restrict__ ef2,
    float* __restrict__ Np, float* __restrict__ Zp) {
  __shared__ __align__(16) char Wt[2][17408];   // 128 rows x 136B (64j bf16 + 8B pad)
  __shared__ __align__(16) char Hb[2][32768];   // 256 rows x 128B, linear, src-swz
  __shared__ __align__(16) char Elds[16384];    // ef2 slab: 2048 x {e,f} f32

  const int tid = threadIdx.x, lane = tid & 63, wave = tid >> 6;
  const int wm = wave >> 2, wn = wave & 3;
  const int lrow = lane & 15, lk16 = (lane >> 4) << 4;
  // XCD remap: same-XCD blocks (bid mod 8) share by -> shared j-window in L2
  const int bid = blockIdx.y * 64 + blockIdx.x;
  const int bx = bid >> 2, by = bid & 3;
  const int I0 = bx * 128;
  const int j0 = by * 2048;

  // --- W staging map: thread -> rows ar+32p (p=0..3), 4-j chunk aj
  const int ar = tid >> 4, aj = tid & 15;
  const int* agp = adj + (size_t)(I0 + ar) * 8192 + j0 + aj * 4;
  float e1p[4], f1p[4];
  #pragma unroll
  for (int p = 0; p < 4; ++p) {
    float2 v = e1f1[I0 + p * 32 + ar];
    e1p[p] = v.x; f1p[p] = v.y;
  }
  const int wwo = ar * 136 + aj * 8;            // + p*4352, + buf

  // --- H DMA: wave -> rows wave*32..+31; lane l -> row +(l>>3),
  //     global chunk (l&7)^(l>>3) (pre-swizzle; LDS stays linear)
  const int l8 = lane >> 3, l7 = lane & 7;
  const short* hdma = hT + (size_t)(wave * 32 + l8) * 8192 + j0 + (l7 ^ l8) * 8;
  const int hlo = wave * 4096;                  // + q*1024, + buf

  // --- frag-read bases
  const int ardo = (wm * 64 + lrow) * 136 + lk16;      // + mi*2176 + kk*64
  const int brdo = (wn * 64 + lrow) * 128;             // + ni*2048 + (c0 ^ kk<<6)
  const int c0   = ((lane >> 4) ^ (lrow & 7)) << 4;

  float4v zero4 = {0.f, 0.f, 0.f, 0.f};
  float4v acc[4][4];
  #pragma unroll
  for (int mi = 0; mi < 4; ++mi)
    #pragma unroll
    for (int ni = 0; ni < 4; ++ni) acc[mi][ni] = zero4;
  float zacc[4] = {0.f, 0.f, 0.f, 0.f};
  int4v ga[4];

  // W-compute for tile T from ga + Elds, writes to DST (Wt buffer base)
#define WCOMP(T, DST)                                                         \
  { const float4v ge0 = *(const float4v*)(Elds + (T) * 512 + aj * 32);        \
    const float4v ge1 = *(const float4v*)(Elds + (T) * 512 + aj * 32 + 16);   \
    _Pragma("unroll")                                                         \
    for (int p = 0; p < 4; ++p) {                                             \
      float w0 = ga[p][0] ? fmaxf(e1p[p] * ge0[0], f1p[p] * ge0[1]) : 1.0f;   \
      float w1 = ga[p][1] ? fmaxf(e1p[p] * ge0[2], f1p[p] * ge0[3]) : 1.0f;   \
      float w2 = ga[p][2] ? fmaxf(e1p[p] * ge1[0], f1p[p] * ge1[1]) : 1.0f;   \
      float w3 = ga[p][3] ? fmaxf(e1p[p] * ge1[2], f1p[p] * ge1[3]) : 1.0f;   \
      zacc[p] += (w0 + w1) + (w2 + w3);                                       \
      int2v pw;                                                               \
      asm("v_cvt_pk_bf16_f32 %0, %1, %2" : "=v"(pw[0]) : "v"(w0), "v"(w1));   \
      asm("v_cvt_pk_bf16_f32 %0, %1, %2" : "=v"(pw[1]) : "v"(w2), "v"(w3));   \
      *(int2v*)((DST) + wwo + p * 4352) = pw;                                 \
    } }

  // --- prologue: ef table -> LDS; tile-0 staging; counted-wait barrier
  {
    const char* esrc = (const char*)(ef2 + j0);
    *(float4v*)(Elds + tid * 32)      = *(const float4v*)(esrc + tid * 32);
    *(float4v*)(Elds + tid * 32 + 16) = *(const float4v*)(esrc + tid * 32 + 16);
  }
  __syncthreads();                              // Elds visible
  #pragma unroll
  for (int p = 0; p < 4; ++p)
    ga[p] = __builtin_nontemporal_load((const int4v*)(agp + (size_t)p * 262144));
  __builtin_amdgcn_sched_barrier(0);            // pin: adj0 issued first
  #pragma unroll
  for (int q = 0; q < 4; ++q)
    dma16(hdma + q * 65536, Hb[0] + hlo + q * 1024);
  __builtin_amdgcn_sched_barrier(0);            // pin: DMAs before adj1
  WCOMP(0, Wt[0]);
  #pragma unroll
  for (int p = 0; p < 4; ++p)
    ga[p] = __builtin_nontemporal_load((const int4v*)(agp + (size_t)p * 262144 + 64));
  __builtin_amdgcn_sched_barrier(0);            // pin: adj1 after DMAs
  asm volatile("s_waitcnt vmcnt(4) lgkmcnt(0)" ::: "memory");
  __builtin_amdgcn_s_barrier();
  __builtin_amdgcn_sched_barrier(0);

  #pragma unroll 2
  for (int s = 0; s < 32; ++s) {
    const int cur = s & 1, nx = cur ^ 1;
    // P1: DMA H(s+1) into Hb[nx]
    if (s < 31) {
      const int so = (s + 1) * 64;              // shorts
      #pragma unroll
      for (int q = 0; q < 4; ++q)
        dma16(hdma + so + q * 65536, Hb[nx] + hlo + q * 1024);
    }
    __builtin_amdgcn_sched_barrier(0);          // pin: DMA group issued here
    // P2: kk=0 frags + 16 MFMA
    short8 af[4], bf[4];
    #pragma unroll
    for (int mi = 0; mi < 4; ++mi) af[mi] = *(const short8*)(Wt[cur] + ardo + mi * 2176);
    #pragma unroll
    for (int ni = 0; ni < 4; ++ni) bf[ni] = *(const short8*)(Hb[cur] + brdo + ni * 2048 + c0);
    #pragma unroll
    for (int mi = 0; mi < 4; ++mi)
      #pragma unroll
      for (int ni = 0; ni < 4; ++ni)
        acc[mi][ni] = __builtin_amdgcn_mfma_f32_16x16x32_bf16(af[mi], bf[ni], acc[mi][ni], 0, 0, 0);
    // P3: W-compute(s+1) -> Wt[nx] (VALU covers the DMA in flight)
    if (s < 31) WCOMP(s + 1, Wt[nx]);
    // P4: issue adj — EVERY s<31 (clamped) so each barrier has exactly 4
    //     adj ops in flight behind the 4 DMAs (vmcnt(4) drains DMAs only)
    if (s < 31) {
      const int sp = (s + 2 < 32) ? s + 2 : 31;
      const int so = sp * 64;                   // ints
      #pragma unroll
      for (int p = 0; p < 4; ++p)
        ga[p] = __builtin_nontemporal_load((const int4v*)(agp + (size_t)p * 262144 + so));
    }
    __builtin_amdgcn_sched_barrier(0);          // pin: adj group after DMAs
    // P5: kk=1 frags + 16 MFMA
    #pragma unroll
    for (int mi = 0; mi < 4; ++mi) af[mi] = *(const short8*)(Wt[cur] + ardo + mi * 2176 + 64);
    #pragma unroll
    for (int ni = 0; ni < 4; ++ni) bf[ni] = *(const short8*)(Hb[cur] + brdo + ni * 2048 + (c0 ^ 64));
    #pragma unroll
    for (int mi = 0; mi < 4; ++mi)
      #pragma unroll
      for (int ni = 0; ni < 4; ++ni)
        acc[mi][ni] = __builtin_amdgcn_mfma_f32_16x16x32_bf16(af[mi], bf[ni], acc[mi][ni], 0, 0, 0);
    // P6: counted drain (DMAs only; adj loads stay in flight) + raw barrier
    if (s < 31) {
      asm volatile("s_waitcnt vmcnt(4) lgkmcnt(0)" ::: "memory");
      __builtin_amdgcn_s_barrier();
      __builtin_amdgcn_sched_barrier(0);
    }
  }
#undef WCOMP

  // Z reduce: per-thread partials -> LDS (alias over Elds) -> 1/row
  __syncthreads();
  float* zl = (float*)Elds;
  #pragma unroll
  for (int p = 0; p < 4; ++p) zl[(ar + p * 32) * 16 + aj] = zacc[p];
  __syncthreads();
  if (tid < 128) {
    float z = 0.f;
    #pragma unroll
    for (int g = 0; g < 16; ++g) z += zl[tid * 16 + g];
    Zp[(size_t)by * 8192 + I0 + tid] = z;
  }

  // N partial store (direct, no atomics)
  float* Npb = Np + (size_t)by * 2097152;
  const int r0 = (lane >> 4) << 2;
  #pragma unroll
  for (int mi = 0; mi < 4; ++mi) {
    const int rowb = I0 + wm * 64 + mi * 16 + r0;
    #pragma unroll
    for (int ni = 0; ni < 4; ++ni) {
      const int col = wn * 64 + ni * 16 + lrow;
      #pragma unroll
      for (int r = 0; r < 4; ++r)
        Npb[(size_t)(rowb + r) * 256 + col] = acc[mi][ni][r];
    }
  }
}

// ---------------------------------------------------------------------------
// Kernel 5: out = elu( (sum_y Np) / (sum_y Zp) )   (4 split-K slabs)
// ---------------------------------------------------------------------------
__global__ __launch_bounds__(256) void k_out(
    const float* __restrict__ Np, const float* __restrict__ Zp,
    float* __restrict__ out) {
  const int idx = blockIdx.x * 256 + threadIdx.x;   // float4 index
  const int i = idx >> 6;                           // row (256 feat = 64 f4)
  float z = 0.f;
  #pragma unroll
  for (int y = 0; y < 4; ++y) z += Zp[y * 8192 + i];
  float4v n = {0.f, 0.f, 0.f, 0.f};
  #pragma unroll
  for (int y = 0; y < 4; ++y) {
    float4v v = ((const float4v*)Np)[(size_t)y * 524288 + idx];
    #pragma unroll
    for (int e = 0; e < 4; ++e) n[e] += v[e];
  }
  const float rz = 1.0f / z;
  float4v o;
  #pragma unroll
  for (int e = 0; e < 4; ++e) {
    float v = n[e] * rz;
    o[e] = (v > 0.f) ? v : expm1f(v);
  }
  ((float4v*)out)[idx] = o;
}

// ---------------------------------------------------------------------------
extern "C" void kernel_launch(void* const* d_in, const int* in_sizes, int n_in,
                              void* d_out, int out_size, void* d_ws, size_t ws_size,
                              hipStream_t stream) {
  const int*   adj = (const int*)d_in[0];
  const float* x   = (const float*)d_in[1];
  const float* w   = (const float*)d_in[2];
  const float* a   = (const float*)d_in[3];
  float* out = (float*)d_out;

  // ws layout (~48 MiB of ~1 GiB). d_out is written only by k_out.
  char* ws = (char*)d_ws;
  short*  hT   = (short*)(ws + 0);          //  4 MiB bf16 h^T [256][8192]
  float*  s1   = (float*)(ws + 4194304);    // 32 KiB
  float*  s2   = (float*)(ws + 4259840);    // 32 KiB
  float2* e1f1 = (float2*)(ws + 4325376);   // 64 KiB
  float2* ef2  = (float2*)(ws + 4390912);   // 64 KiB
  float*  Zp   = (float*)(ws + 4456448);    // 128 KiB (4 x 8192)
  float*  Np   = (float*)(ws + 16777216);   // 32 MiB (4 x 8192 x 256)

  k_hgemm  <<<256, 256, 0, stream>>>(x, w, a, hT, s1, s2);
  k_scores2<<<32, 256, 0, stream>>>(s1, s2, e1f1, ef2);
  k_gat    <<<dim3(64, 4), 512, 0, stream>>>(adj, hT, e1f1, ef2, Np, Zp);
  k_out    <<<2048, 256, 0, stream>>>(Np, Zp, out);
}